// Round 1
// baseline (846.259 us; speedup 1.0000x reference)
//
#include <hip/hip_runtime.h>

#define CIN 48
#define COUT 48
#define NPIX 16384  // 128*128

// ---------------------------------------------------------------------------
// K1: Gabor weights w[oc][i][9]  (oi = oc*CIN+i flat, matches (COUT,CIN) arrays)
// ---------------------------------------------------------------------------
__global__ __launch_bounds__(256) void gabor_k(
    const float* __restrict__ freq, const float* __restrict__ theta,
    const float* __restrict__ sigma, const float* __restrict__ psi,
    const float* __restrict__ f0, const float* __restrict__ theta0,
    float* __restrict__ wout)
{
  int idx = blockIdx.x * 256 + threadIdx.x;
  if (idx >= COUT * CIN * 9) return;
  int k = idx % 9;
  int oi = idx / 9;
  int a = k / 3, b = k % 3;           // a = KH index, b = KW index
  // linspace(-1, 2, 3) = {-1, 0.5, 2}
  float Yv = (a == 0) ? -1.0f : ((a == 1) ? 0.5f : 2.0f);
  float Xv = (b == 0) ? -1.0f : ((b == 1) ? 0.5f : 2.0f);
  float th = theta[oi], sg = sigma[oi], fr = freq[oi], ps = psi[oi];
  float F0 = f0[oi], th0 = theta0[oi];
  float c = cosf(th), s = sinf(th);
  float rotx =  Xv * c + Yv * s;
  float roty = -Xv * s + Yv * c;
  float r = sqrtf(rotx * rotx + roty * roty + 0.001f);
  float denom = 2.0f * logf(sg / F0);
  float t1 = (logf(r) - logf(F0)) / denom;
  float g_rad = expf(-t1 * t1);
  float dth = th - th0;
  float g_ang = expf(-dth * dth / (2.0f * sg * sg));
  float g = g_rad * g_ang * cosf(fr * r + ps) / (6.283185307179586f * sg * sg);
  wout[idx] = g;
}

// ---------------------------------------------------------------------------
// K2: circulant band-limit vector a[d] = (1/128) sum_{u=34}^{93} e^{2pi i u d/128}
// ---------------------------------------------------------------------------
__global__ void circ_k(float* __restrict__ ar, float* __restrict__ ai)
{
  int d = threadIdx.x;  // 128 threads
  float sr = 0.f, si = 0.f;
  for (int u = 34; u < 94; ++u) {
    int m = (u * d) & 127;                       // exact integer mod -> accurate angle
    float ang = (float)m * 0.049087385212340526f; // 2*pi/128
    sr += cosf(ang);
    si += sinf(ang);
  }
  ar[d] = sr * (1.0f / 128.0f);
  ai[d] = si * (1.0f / 128.0f);
}

// ---------------------------------------------------------------------------
// K3a: Ur[i][y][j] = sum_x X[i][y][x] * ar[(j-x)&127]   (and Ui with ai)
//      stored packed float2 (Ur, Ui) at Up[i][y][j], natural layout.
// block = (ygroup of 32 rows, i); threads: t -> j = t&127, yslot = t>>7 (16 rows each)
// ---------------------------------------------------------------------------
__global__ __launch_bounds__(256) void stage1_k(
    const float* __restrict__ x, const float* __restrict__ arr,
    const float* __restrict__ aii, float2* __restrict__ Up)
{
  __shared__ float Xs[32 * 128];   // 16 KB
  __shared__ float ars[128], ais[128];
  int yg = blockIdx.x, i = blockIdx.y;
  int t = threadIdx.x;
  const float* Xi = x + i * NPIX + yg * 32 * 128;
  for (int p = t; p < 4096; p += 256) Xs[p] = Xi[p];
  if (t < 128) { ars[t] = arr[t]; ais[t] = aii[t]; }
  __syncthreads();
  int j = t & 127;
  int ysl = t >> 7;                // 0 or 1
  float accr[16], acci[16];
#pragma unroll
  for (int yy = 0; yy < 16; ++yy) { accr[yy] = 0.f; acci[yy] = 0.f; }
  for (int xx = 0; xx < 128; ++xx) {
    float tr = ars[(j - xx) & 127];
    float ti = ais[(j - xx) & 127];
#pragma unroll
    for (int yy = 0; yy < 16; ++yy) {
      float xv = Xs[(ysl * 16 + yy) * 128 + xx];   // wave-uniform -> LDS broadcast
      accr[yy] += xv * tr;
      acci[yy] += xv * ti;
    }
  }
  float2* UpI = Up + i * NPIX;
  int ybase = yg * 32 + ysl * 16;
#pragma unroll
  for (int yy = 0; yy < 16; ++yy)
    UpI[(ybase + yy) * 128 + j] = make_float2(accr[yy], acci[yy]);  // coalesced in j
}

// ---------------------------------------------------------------------------
// K3b: yf[i][y'][x] = sum_y ar[(y'-y)&127]*Ur[i][y][x] - ai[(y'-y)&127]*Ui[i][y][x]
// block = (xgroup of 32 cols, i); threads: t -> y' = t&127, xslot = t>>7 (16 cols each)
// ---------------------------------------------------------------------------
__global__ __launch_bounds__(256) void stage2_k(
    const float2* __restrict__ Up, const float* __restrict__ arr,
    const float* __restrict__ aii, float* __restrict__ yf)
{
  __shared__ float2 Us[128 * 32];  // [y][jj], 32 KB
  __shared__ float ars[128], ais[128];
  int jg = blockIdx.x, i = blockIdx.y;
  int t = threadIdx.x;
  const float2* UpI = Up + i * NPIX;
  for (int p = t; p < 4096; p += 256) {
    int y = p >> 5, jj = p & 31;
    Us[p] = UpI[y * 128 + jg * 32 + jj];  // 256B contiguous per row
  }
  if (t < 128) { ars[t] = arr[t]; ais[t] = aii[t]; }
  __syncthreads();
  int yp = t & 127;     // y'
  int xsl = t >> 7;     // 0 or 1
  float acc[16];
#pragma unroll
  for (int xx = 0; xx < 16; ++xx) acc[xx] = 0.f;
  for (int y = 0; y < 128; ++y) {
    float tr = ars[(yp - y) & 127];   // stride-1 across lanes
    float ti = ais[(yp - y) & 127];
#pragma unroll
    for (int xx = 0; xx < 16; ++xx) {
      float2 u = Us[y * 32 + xsl * 16 + xx];  // wave-uniform -> broadcast
      acc[xx] += u.x * tr - u.y * ti;
    }
  }
  float* yfI = yf + i * NPIX;
  int xb = jg * 32 + xsl * 16;
#pragma unroll
  for (int xx = 0; xx < 16; ++xx)
    yfI[yp * 128 + xb + xx] = acc[xx];
}

// ---------------------------------------------------------------------------
// K4: fused  x_filtered = w[o,i] circularly correlated with yf[i]  (in LDS tile)
//     then   out[o,oc] += zero-padded 3x3 corr of x_filtered with w[oc,i]
// block = (xtile, ytile, o), 256 threads = 16x16 pixels, 48 oc accumulators/thread
// ---------------------------------------------------------------------------
__global__ __launch_bounds__(256) void conv2_k(
    const float* __restrict__ yf, const float* __restrict__ wts,
    float* __restrict__ out)
{
  __shared__ float yft[20 * 20];   // yf tile with halo 3 up/left, 1 down/right
  __shared__ float xft[18 * 20];   // x_filtered tile with halo 1, pitch 20
  int o  = blockIdx.z;
  int y0 = blockIdx.y * 16, x0 = blockIdx.x * 16;
  int t  = threadIdx.x;
  int tx = t & 15, ty = t >> 4;
  float acc[COUT];
#pragma unroll
  for (int c = 0; c < COUT; ++c) acc[c] = 0.f;

  for (int i = 0; i < CIN; ++i) {
    // stage yf tile (circular indexing - inner conv is circular)
    for (int p = t; p < 400; p += 256) {
      int rr = p / 20, cc = p % 20;
      int gr = (y0 - 3 + rr) & 127;
      int gc = (x0 - 3 + cc) & 127;
      yft[p] = yf[i * NPIX + gr * 128 + gc];
    }
    __syncthreads();

    // x_filtered tile: rows y0-1..y0+16, cols x0-1..x0+16; zero outside [0,128)
    const float* wo = wts + (o * CIN + i) * 9;   // wave-uniform -> s_load
    float w0 = wo[0], w1 = wo[1], w2 = wo[2], w3 = wo[3], w4 = wo[4],
          w5 = wo[5], w6 = wo[6], w7 = wo[7], w8 = wo[8];
    for (int p = t; p < 324; p += 256) {
      int rr = p / 18, cc = p % 18;
      int gr = y0 - 1 + rr, gc = x0 - 1 + cc;
      float v = 0.f;
      if (gr >= 0 && gr < 128 && gc >= 0 && gc < 128) {
        v = w0 * yft[(rr + 2) * 20 + cc + 2] + w1 * yft[(rr + 2) * 20 + cc + 1] + w2 * yft[(rr + 2) * 20 + cc]
          + w3 * yft[(rr + 1) * 20 + cc + 2] + w4 * yft[(rr + 1) * 20 + cc + 1] + w5 * yft[(rr + 1) * 20 + cc]
          + w6 * yft[(rr + 0) * 20 + cc + 2] + w7 * yft[(rr + 0) * 20 + cc + 1] + w8 * yft[(rr + 0) * 20 + cc];
      }
      xft[rr * 20 + cc] = v;
    }
    __syncthreads();

    // accumulate all oc
    float xv[9];
#pragma unroll
    for (int dy = 0; dy < 3; ++dy)
#pragma unroll
      for (int dx = 0; dx < 3; ++dx)
        xv[dy * 3 + dx] = xft[(ty + dy) * 20 + tx + dx];
#pragma unroll
    for (int oc = 0; oc < COUT; ++oc) {
      const float* wr = wts + (oc * CIN + i) * 9;  // wave-uniform -> s_load
      float s = wr[0] * xv[0] + wr[1] * xv[1] + wr[2] * xv[2]
              + wr[3] * xv[3] + wr[4] * xv[4] + wr[5] * xv[5]
              + wr[6] * xv[6] + wr[7] * xv[7] + wr[8] * xv[8];
      acc[oc] += s;
    }
    __syncthreads();   // protect xft before next iteration's overwrite
  }

  int y = y0 + ty, xcol = x0 + tx;
#pragma unroll
  for (int oc = 0; oc < COUT; ++oc)
    out[((o * COUT + oc) * 128 + y) * 128 + xcol] = acc[oc];
}

// ---------------------------------------------------------------------------
extern "C" void kernel_launch(void* const* d_in, const int* in_sizes, int n_in,
                              void* d_out, int out_size, void* d_ws, size_t ws_size,
                              hipStream_t stream)
{
  const float* x      = (const float*)d_in[0];
  const float* freq   = (const float*)d_in[1];
  const float* theta  = (const float*)d_in[2];
  const float* sigma  = (const float*)d_in[3];
  const float* psi    = (const float*)d_in[4];
  const float* f0     = (const float*)d_in[5];
  const float* theta0 = (const float*)d_in[6];
  float* out = (float*)d_out;
  float* ws  = (float*)d_ws;

  // ws layout (floats): w[20736] | ar[128] | ai[128] | pad | Up[48*16384*2] | yf[48*16384]
  float*  w  = ws;
  float*  ar = ws + 20736;
  float*  ai = ws + 20864;
  float2* Up = (float2*)(ws + 21248);
  float*  yf = ws + 21248 + CIN * NPIX * 2;
  // total ~9.6 MB of workspace

  gabor_k<<<dim3(81), dim3(256), 0, stream>>>(freq, theta, sigma, psi, f0, theta0, w);
  circ_k<<<dim3(1), dim3(128), 0, stream>>>(ar, ai);
  stage1_k<<<dim3(4, 48), dim3(256), 0, stream>>>(x, ar, ai, Up);
  stage2_k<<<dim3(4, 48), dim3(256), 0, stream>>>(Up, ar, ai, yf);
  conv2_k<<<dim3(8, 8, 48), dim3(256), 0, stream>>>(yf, w, out);
}

// Round 4
// 198.508 us; speedup vs baseline: 4.2631x; 4.2631x over previous
//
#include <hip/hip_runtime.h>

#define CIN 48
#define COUT 48
#define NPIX 16384  // 128*128

typedef float f32x4 __attribute__((ext_vector_type(4)));
typedef short bf16x8 __attribute__((ext_vector_type(8)));

__device__ __forceinline__ unsigned short f2bf(float f) {
  unsigned u = __float_as_uint(f);
  unsigned r = (u + 0x7FFFu + ((u >> 16) & 1u)) >> 16;  // RNE
  return (unsigned short)r;
}

// ---------------------------------------------------------------------------
// K1: Gabor weights. Writes f32 w[oc][i][9] AND padded bf16 table
//     wbf64[(k*48+oc)*64 + i], i in [0,48) real, [48,64) zero.
// ---------------------------------------------------------------------------
__global__ __launch_bounds__(256) void gabor_k(
    const float* __restrict__ freq, const float* __restrict__ theta,
    const float* __restrict__ sigma, const float* __restrict__ psi,
    const float* __restrict__ f0, const float* __restrict__ theta0,
    float* __restrict__ wout, unsigned short* __restrict__ wbf64)
{
  int idx = blockIdx.x * 256 + threadIdx.x;
  if (idx < 432 * 16) {                      // zero the K-pad region
    wbf64[(idx >> 4) * 64 + 48 + (idx & 15)] = 0;
  }
  if (idx >= COUT * CIN * 9) return;
  int k = idx % 9;
  int oi = idx / 9;
  int oc = oi / CIN, ic = oi % CIN;
  int a = k / 3, b = k % 3;
  float Yv = (a == 0) ? -1.0f : ((a == 1) ? 0.5f : 2.0f);
  float Xv = (b == 0) ? -1.0f : ((b == 1) ? 0.5f : 2.0f);
  float th = theta[oi], sg = sigma[oi], fr = freq[oi], ps = psi[oi];
  float F0 = f0[oi], th0 = theta0[oi];
  float c = cosf(th), s = sinf(th);
  float rotx =  Xv * c + Yv * s;
  float roty = -Xv * s + Yv * c;
  float r = sqrtf(rotx * rotx + roty * roty + 0.001f);
  float denom = 2.0f * logf(sg / F0);
  float t1 = (logf(r) - logf(F0)) / denom;
  float g_rad = expf(-t1 * t1);
  float dth = th - th0;
  float g_ang = expf(-dth * dth / (2.0f * sg * sg));
  float g = g_rad * g_ang * cosf(fr * r + ps) / (6.283185307179586f * sg * sg);
  wout[idx] = g;
  wbf64[(k * 48 + oc) * 64 + ic] = f2bf(g);
}

// ---------------------------------------------------------------------------
// K2: circulant band-limit vector
// ---------------------------------------------------------------------------
__global__ void circ_k(float* __restrict__ ar, float* __restrict__ ai)
{
  int d = threadIdx.x;
  float sr = 0.f, si = 0.f;
  for (int u = 34; u < 94; ++u) {
    int m = (u * d) & 127;
    float ang = (float)m * 0.049087385212340526f;
    sr += cosf(ang);
    si += sinf(ang);
  }
  ar[d] = sr * (1.0f / 128.0f);
  ai[d] = si * (1.0f / 128.0f);
}

// ---------------------------------------------------------------------------
// K3a / K3b: circulant band-limit applied along x then y (unchanged, passing)
// ---------------------------------------------------------------------------
__global__ __launch_bounds__(256) void stage1_k(
    const float* __restrict__ x, const float* __restrict__ arr,
    const float* __restrict__ aii, float2* __restrict__ Up)
{
  __shared__ float Xs[32 * 128];
  __shared__ float ars[128], ais[128];
  int yg = blockIdx.x, i = blockIdx.y;
  int t = threadIdx.x;
  const float* Xi = x + i * NPIX + yg * 32 * 128;
  for (int p = t; p < 4096; p += 256) Xs[p] = Xi[p];
  if (t < 128) { ars[t] = arr[t]; ais[t] = aii[t]; }
  __syncthreads();
  int j = t & 127;
  int ysl = t >> 7;
  float accr[16], acci[16];
#pragma unroll
  for (int yy = 0; yy < 16; ++yy) { accr[yy] = 0.f; acci[yy] = 0.f; }
  for (int xx = 0; xx < 128; ++xx) {
    float tr = ars[(j - xx) & 127];
    float ti = ais[(j - xx) & 127];
#pragma unroll
    for (int yy = 0; yy < 16; ++yy) {
      float xv = Xs[(ysl * 16 + yy) * 128 + xx];
      accr[yy] += xv * tr;
      acci[yy] += xv * ti;
    }
  }
  float2* UpI = Up + i * NPIX;
  int ybase = yg * 32 + ysl * 16;
#pragma unroll
  for (int yy = 0; yy < 16; ++yy)
    UpI[(ybase + yy) * 128 + j] = make_float2(accr[yy], acci[yy]);
}

__global__ __launch_bounds__(256) void stage2_k(
    const float2* __restrict__ Up, const float* __restrict__ arr,
    const float* __restrict__ aii, float* __restrict__ yf)
{
  __shared__ float2 Us[128 * 32];
  __shared__ float ars[128], ais[128];
  int jg = blockIdx.x, i = blockIdx.y;
  int t = threadIdx.x;
  const float2* UpI = Up + i * NPIX;
  for (int p = t; p < 4096; p += 256) {
    int y = p >> 5, jj = p & 31;
    Us[p] = UpI[y * 128 + jg * 32 + jj];
  }
  if (t < 128) { ars[t] = arr[t]; ais[t] = aii[t]; }
  __syncthreads();
  int yp = t & 127;
  int xsl = t >> 7;
  float acc[16];
#pragma unroll
  for (int xx = 0; xx < 16; ++xx) acc[xx] = 0.f;
  for (int y = 0; y < 128; ++y) {
    float tr = ars[(yp - y) & 127];
    float ti = ais[(yp - y) & 127];
#pragma unroll
    for (int xx = 0; xx < 16; ++xx) {
      float2 u = Us[y * 32 + xsl * 16 + xx];
      acc[xx] += u.x * tr - u.y * ti;
    }
  }
  float* yfI = yf + i * NPIX;
  int xb = jg * 32 + xsl * 16;
#pragma unroll
  for (int xx = 0; xx < 16; ++xx)
    yfI[yp * 128 + xb + xx] = acc[xx];
}

// ---------------------------------------------------------------------------
// K4: fused XF-build + MFMA GEMM (x32-only, K padded to 64).
//  block = (xtile, ytile, o), 256 threads = 4 waves.
//  LDS: XF[324 px][72 shorts pitch] = 46656 B (i 48..63 zeroed)
//  A-frags load direct from global wbf64 (L1-resident 55 KB table).
// ---------------------------------------------------------------------------
__global__ __launch_bounds__(256) void conv2_k(
    const float* __restrict__ yf, const float* __restrict__ wts,
    const unsigned short* __restrict__ wbf64, float* __restrict__ out)
{
  __shared__ __align__(16) short XF[324 * 72];   // [p][i] pitch 72 shorts (144 B)

  int o  = blockIdx.z;
  int y0 = blockIdx.y * 16, x0 = blockIdx.x * 16;
  int tid = threadIdx.x;

  // ---- phase 0: zero the K-pad lanes (i 48..63) ----
  for (int p = tid; p < 324; p += 256) {
    *(bf16x8*)(XF + p * 72 + 48) = (bf16x8){0,0,0,0,0,0,0,0};
    *(bf16x8*)(XF + p * 72 + 56) = (bf16x8){0,0,0,0,0,0,0,0};
  }

  // ---- phase 1: build XF tile (18x18, halo 1) for all 48 i ----
  // xf(y,x) = sum_{dy,dx in 0..2} w[dy,dx] * yf((y-dy)&127, (x-dx)&127)
  for (int s = tid; s < 432; s += 256) {
    int i = s / 9, cp = s - i * 9;
    const float* Wp = wts + (o * CIN + i) * 9;
    float W0 = Wp[0], W1 = Wp[1], W2 = Wp[2], W3 = Wp[3], W4 = Wp[4],
          W5 = Wp[5], W6 = Wp[6], W7 = Wp[7], W8 = Wp[8];
    const float* yfp = yf + i * NPIX;
    int c0 = (x0 - 4 + 2 * cp) & 127;   // even -> aligned float2, wrap-safe
    int c1 = (c0 + 2) & 127;
    int c2 = (c0 + 4) & 127;
    float Rold[6], Rmid[6], Rnew[6];
    {
      const float* rp = yfp + ((y0 - 3) & 127) * 128;
      float2 a = *(const float2*)(rp + c0);
      float2 b = *(const float2*)(rp + c1);
      float2 c = *(const float2*)(rp + c2);
      Rold[0]=a.x; Rold[1]=a.y; Rold[2]=b.x; Rold[3]=b.y; Rold[4]=c.x; Rold[5]=c.y;
      rp = yfp + ((y0 - 2) & 127) * 128;
      a = *(const float2*)(rp + c0);
      b = *(const float2*)(rp + c1);
      c = *(const float2*)(rp + c2);
      Rmid[0]=a.x; Rmid[1]=a.y; Rmid[2]=b.x; Rmid[3]=b.y; Rmid[4]=c.x; Rmid[5]=c.y;
    }
    for (int rr = 0; rr < 18; ++rr) {
      const float* rp = yfp + ((y0 - 1 + rr) & 127) * 128;
      float2 a = *(const float2*)(rp + c0);
      float2 b = *(const float2*)(rp + c1);
      float2 c = *(const float2*)(rp + c2);
      Rnew[0]=a.x; Rnew[1]=a.y; Rnew[2]=b.x; Rnew[3]=b.y; Rnew[4]=c.x; Rnew[5]=c.y;
      int y = y0 - 1 + rr;
      bool yok = (y >= 0) && (y < 128);
#pragma unroll
      for (int j = 0; j < 2; ++j) {
        int xg = x0 - 1 + 2 * cp + j;
        float v = 0.f;
        if (yok && xg >= 0 && xg < 128) {
          v = W0 * Rnew[j + 3] + W1 * Rnew[j + 2] + W2 * Rnew[j + 1]
            + W3 * Rmid[j + 3] + W4 * Rmid[j + 2] + W5 * Rmid[j + 1]
            + W6 * Rold[j + 3] + W7 * Rold[j + 2] + W8 * Rold[j + 1];
        }
        XF[(rr * 18 + 2 * cp + j) * 72 + i] = (short)f2bf(v);
      }
#pragma unroll
      for (int q = 0; q < 6; ++q) { Rold[q] = Rmid[q]; Rmid[q] = Rnew[q]; }
    }
  }
  __syncthreads();

  // ---- phase 2: MFMA GEMM, 16x16x32_bf16 only ----
  int wv = tid >> 6, lane = tid & 63;
  int tx = lane & 15, gq = lane >> 4;   // gq in 0..3
  f32x4 acc[4][3];
#pragma unroll
  for (int nn = 0; nn < 4; ++nn)
#pragma unroll
    for (int m = 0; m < 3; ++m) acc[nn][m] = (f32x4){0.f, 0.f, 0.f, 0.f};

  for (int k = 0; k < 9; ++k) {
    int dy = k / 3, dx = k - dy * 3;
    bf16x8 A0[3], A1[3];
#pragma unroll
    for (int m = 0; m < 3; ++m) {
      const unsigned short* ap = wbf64 + (k * 48 + m * 16 + tx) * 64;
      A0[m] = *(const bf16x8*)(ap + gq * 8);        // i = 8gq..8gq+7
      A1[m] = *(const bf16x8*)(ap + 32 + gq * 8);   // i = 32+8gq.. (pad zeros)
    }
#pragma unroll
    for (int nn = 0; nn < 4; ++nn) {
      int n = wv * 4 + nn;   // output y-row within 16x16 tile
      const short* bp = XF + ((n + dy) * 18 + tx + dx) * 72;
      bf16x8 B0 = *(const bf16x8*)(bp + gq * 8);
      bf16x8 B1 = *(const bf16x8*)(bp + 32 + gq * 8);
#pragma unroll
      for (int m = 0; m < 3; ++m) {
        acc[nn][m] = __builtin_amdgcn_mfma_f32_16x16x32_bf16(A0[m], B0, acc[nn][m], 0, 0, 0);
        acc[nn][m] = __builtin_amdgcn_mfma_f32_16x16x32_bf16(A1[m], B1, acc[nn][m], 0, 0, 0);
      }
    }
  }

  // ---- epilogue: C frag layout col=lane&15 (pixel x), row=gq*4+r (oc) ----
#pragma unroll
  for (int nn = 0; nn < 4; ++nn) {
    int y = y0 + wv * 4 + nn;
#pragma unroll
    for (int m = 0; m < 3; ++m) {
#pragma unroll
      for (int r = 0; r < 4; ++r) {
        int oc = m * 16 + gq * 4 + r;
        out[((size_t)(o * COUT + oc) << 14) + (y << 7) + x0 + tx] = acc[nn][m][r];
      }
    }
  }
}

// ---------------------------------------------------------------------------
extern "C" void kernel_launch(void* const* d_in, const int* in_sizes, int n_in,
                              void* d_out, int out_size, void* d_ws, size_t ws_size,
                              hipStream_t stream)
{
  const float* x      = (const float*)d_in[0];
  const float* freq   = (const float*)d_in[1];
  const float* theta  = (const float*)d_in[2];
  const float* sigma  = (const float*)d_in[3];
  const float* psi    = (const float*)d_in[4];
  const float* f0     = (const float*)d_in[5];
  const float* theta0 = (const float*)d_in[6];
  float* out = (float*)d_out;
  float* ws  = (float*)d_ws;

  // ws layout (floats):
  // w[20736] | ar[128] | ai[128] | pad | Up[48*16384*2] | yf[48*16384] | wbf64 (13824 floats)
  float*  w   = ws;
  float*  ar  = ws + 20736;
  float*  ai  = ws + 20864;
  float2* Up  = (float2*)(ws + 21248);
  float*  yf  = ws + 21248 + CIN * NPIX * 2;
  unsigned short* wbf64 = (unsigned short*)(ws + 21248 + CIN * NPIX * 3);

  gabor_k<<<dim3(81), dim3(256), 0, stream>>>(freq, theta, sigma, psi, f0, theta0, w, wbf64);
  circ_k<<<dim3(1), dim3(128), 0, stream>>>(ar, ai);
  stage1_k<<<dim3(4, 48), dim3(256), 0, stream>>>(x, ar, ai, Up);
  stage2_k<<<dim3(4, 48), dim3(256), 0, stream>>>(Up, ar, ai, yf);
  conv2_k<<<dim3(8, 8, 48), dim3(256), 0, stream>>>(yf, w, wbf64, out);
}

// Round 6
// 184.184 us; speedup vs baseline: 4.5946x; 1.0778x over previous
//
#include <hip/hip_runtime.h>

#define CIN 48
#define COUT 48
#define NPIX 16384  // 128*128

typedef float f32x4 __attribute__((ext_vector_type(4)));
typedef short bf16x8 __attribute__((ext_vector_type(8)));

__device__ __forceinline__ unsigned short f2bf(float f) {
  unsigned u = __float_as_uint(f);
  unsigned r = (u + 0x7FFFu + ((u >> 16) & 1u)) >> 16;  // RNE
  return (unsigned short)r;
}

// ---------------------------------------------------------------------------
// K1: Gabor weights. Writes f32 w[oc][i][9] AND padded bf16 table
//     wbf64[(k*48+oc)*64 + i], i in [0,48) real, [48,64) zero.
// ---------------------------------------------------------------------------
__global__ __launch_bounds__(256) void gabor_k(
    const float* __restrict__ freq, const float* __restrict__ theta,
    const float* __restrict__ sigma, const float* __restrict__ psi,
    const float* __restrict__ f0, const float* __restrict__ theta0,
    float* __restrict__ wout, unsigned short* __restrict__ wbf64)
{
  int idx = blockIdx.x * 256 + threadIdx.x;
  if (idx < 432 * 16) {                      // zero the K-pad region
    wbf64[(idx >> 4) * 64 + 48 + (idx & 15)] = 0;
  }
  if (idx >= COUT * CIN * 9) return;
  int k = idx % 9;
  int oi = idx / 9;
  int oc = oi / CIN, ic = oi % CIN;
  int a = k / 3, b = k % 3;
  float Yv = (a == 0) ? -1.0f : ((a == 1) ? 0.5f : 2.0f);
  float Xv = (b == 0) ? -1.0f : ((b == 1) ? 0.5f : 2.0f);
  float th = theta[oi], sg = sigma[oi], fr = freq[oi], ps = psi[oi];
  float F0 = f0[oi], th0 = theta0[oi];
  float c = cosf(th), s = sinf(th);
  float rotx =  Xv * c + Yv * s;
  float roty = -Xv * s + Yv * c;
  float r = sqrtf(rotx * rotx + roty * roty + 0.001f);
  float denom = 2.0f * logf(sg / F0);
  float t1 = (logf(r) - logf(F0)) / denom;
  float g_rad = expf(-t1 * t1);
  float dth = th - th0;
  float g_ang = expf(-dth * dth / (2.0f * sg * sg));
  float g = g_rad * g_ang * cosf(fr * r + ps) / (6.283185307179586f * sg * sg);
  wout[idx] = g;
  wbf64[(k * 48 + oc) * 64 + ic] = f2bf(g);
}

// ---------------------------------------------------------------------------
// K2: circulant band-limit vector
// ---------------------------------------------------------------------------
__global__ void circ_k(float* __restrict__ ar, float* __restrict__ ai)
{
  int d = threadIdx.x;
  float sr = 0.f, si = 0.f;
  for (int u = 34; u < 94; ++u) {
    int m = (u * d) & 127;
    float ang = (float)m * 0.049087385212340526f;
    sr += cosf(ang);
    si += sinf(ang);
  }
  ar[d] = sr * (1.0f / 128.0f);
  ai[d] = si * (1.0f / 128.0f);
}

// ---------------------------------------------------------------------------
// K3a: row band-limit. grid (8, 48): 16 rows per block.
// ---------------------------------------------------------------------------
__global__ __launch_bounds__(256) void stage1_k(
    const float* __restrict__ x, const float* __restrict__ arr,
    const float* __restrict__ aii, float2* __restrict__ Up)
{
  __shared__ float Xs[16 * 128];
  __shared__ float ars[128], ais[128];
  int yg = blockIdx.x, i = blockIdx.y;
  int t = threadIdx.x;
  const float* Xi = x + i * NPIX + yg * 16 * 128;
  for (int p = t; p < 2048; p += 256) Xs[p] = Xi[p];
  if (t < 128) { ars[t] = arr[t]; ais[t] = aii[t]; }
  __syncthreads();
  int j = t & 127;
  int ysl = t >> 7;
  float accr[8], acci[8];
#pragma unroll
  for (int yy = 0; yy < 8; ++yy) { accr[yy] = 0.f; acci[yy] = 0.f; }
  for (int xx = 0; xx < 128; ++xx) {
    float tr = ars[(j - xx) & 127];
    float ti = ais[(j - xx) & 127];
#pragma unroll
    for (int yy = 0; yy < 8; ++yy) {
      float xv = Xs[(ysl * 8 + yy) * 128 + xx];
      accr[yy] += xv * tr;
      acci[yy] += xv * ti;
    }
  }
  float2* UpI = Up + i * NPIX;
  int ybase = yg * 16 + ysl * 8;
#pragma unroll
  for (int yy = 0; yy < 8; ++yy)
    UpI[(ybase + yy) * 128 + j] = make_float2(accr[yy], acci[yy]);
}

// ---------------------------------------------------------------------------
// K3b: column band-limit. grid (8, 48): 16 cols per block.
// ---------------------------------------------------------------------------
__global__ __launch_bounds__(256) void stage2_k(
    const float2* __restrict__ Up, const float* __restrict__ arr,
    const float* __restrict__ aii, float* __restrict__ yf)
{
  __shared__ float2 Us[128 * 16];
  __shared__ float ars[128], ais[128];
  int jg = blockIdx.x, i = blockIdx.y;
  int t = threadIdx.x;
  const float2* UpI = Up + i * NPIX;
  for (int p = t; p < 2048; p += 256) {
    int y = p >> 4, jj = p & 15;
    Us[p] = UpI[y * 128 + jg * 16 + jj];
  }
  if (t < 128) { ars[t] = arr[t]; ais[t] = aii[t]; }
  __syncthreads();
  int yp = t & 127;
  int xsl = t >> 7;
  float acc[8];
#pragma unroll
  for (int xx = 0; xx < 8; ++xx) acc[xx] = 0.f;
  for (int y = 0; y < 128; ++y) {
    float tr = ars[(yp - y) & 127];
    float ti = ais[(yp - y) & 127];
#pragma unroll
    for (int xx = 0; xx < 8; ++xx) {
      float2 u = Us[y * 16 + xsl * 8 + xx];
      acc[xx] += u.x * tr - u.y * ti;
    }
  }
  float* yfI = yf + i * NPIX;
  int xb = jg * 16 + xsl * 8;
#pragma unroll
  for (int xx = 0; xx < 8; ++xx)
    yfI[yp * 128 + xb + xx] = acc[xx];
}

// ---------------------------------------------------------------------------
// K4: fused XF-build + MFMA GEMM.
//  LDS: XF[324 px][56 shorts] + 16-short zero tail = 36320 B -> 3 blocks/CU.
//  INVARIANT: every LDS location reachable by a B-fragment read is WRITTEN:
//    i in [0,48) = data; [48,56) = zeroed pad (phase 0); row-324 tail zeroed.
//    (0 x uninit-LDS can be 0 x Inf = NaN -> R5 failure.)
//  Phase 1: 240 width-4 strips, static 3-row register rotation, full unroll.
//  Phase 2: 16x16x32_bf16 only; A zero-padded i>=48; A double-buffered.
// ---------------------------------------------------------------------------
__global__ __launch_bounds__(256, 3) void conv2_k(
    const float* __restrict__ yf, const float* __restrict__ wts,
    const unsigned short* __restrict__ wbf64, float* __restrict__ out)
{
  __shared__ __align__(16) short XF[324 * 56 + 16];  // pitch 56 shorts (112 B)

  int o  = blockIdx.z;
  int y0 = blockIdx.y * 16, x0 = blockIdx.x * 16;
  int tid = threadIdx.x;

  // ---- phase 0: zero per-row pad i=[48,56) and the spill tail ----
  for (int p = tid; p < 324; p += 256)
    *(bf16x8*)(XF + p * 56 + 48) = (bf16x8){0,0,0,0,0,0,0,0};
  if (tid < 16) XF[324 * 56 + tid] = 0;

  // ---- phase 1: build XF tile (18x18, halo 1) for all 48 i ----
  // xf(y,x) = sum_{dy,dx in 0..2} w[dy,dx] * yf((y-dy)&127, (x-dx)&127)
  // strip: i = s/5, sp = s%5 -> px cols cidx = 4sp+j (j=0..3, cidx<18)
  // 8-wide register rows based at cb = (x0-4+4sp)&127:
  //   yf(row, x-dx) = R[3+j-dx], x = x0-1+4sp+j
  if (tid < 240) {
    int s = tid;
    int i = s / 5, sp = s - i * 5;
    const float* Wp = wts + (o * CIN + i) * 9;
    float W0 = Wp[0], W1 = Wp[1], W2 = Wp[2], W3 = Wp[3], W4 = Wp[4],
          W5 = Wp[5], W6 = Wp[6], W7 = Wp[7], W8 = Wp[8];
    const float* yfp = yf + i * NPIX;
    int cb = (x0 - 4 + 4 * sp) & 127;   // even -> aligned float2, wrap-safe
    float Ra[8], Rb[8], Rc[8];

#define LOADROW(dst, ry) { \
    const float* rp_ = yfp + (((ry) & 127) << 7); \
    float2 q0_ = *(const float2*)(rp_ + cb); \
    float2 q1_ = *(const float2*)(rp_ + ((cb + 2) & 127)); \
    float2 q2_ = *(const float2*)(rp_ + ((cb + 4) & 127)); \
    float2 q3_ = *(const float2*)(rp_ + ((cb + 6) & 127)); \
    dst[0]=q0_.x; dst[1]=q0_.y; dst[2]=q1_.x; dst[3]=q1_.y; \
    dst[4]=q2_.x; dst[5]=q2_.y; dst[6]=q3_.x; dst[7]=q3_.y; }

#define EMIT(rr, R2_, R1_, R0_) { \
    int y_ = y0 - 1 + (rr); \
    bool yok_ = (y_ >= 0) && (y_ < 128); \
    _Pragma("unroll") \
    for (int j = 0; j < 4; ++j) { \
      int cidx_ = 4 * sp + j; \
      if (cidx_ < 18) { \
        int xg_ = x0 - 1 + cidx_; \
        float v_ = 0.f; \
        if (yok_ && xg_ >= 0 && xg_ < 128) { \
          v_ = W0 * R0_[j + 3] + W1 * R0_[j + 2] + W2 * R0_[j + 1] \
             + W3 * R1_[j + 3] + W4 * R1_[j + 2] + W5 * R1_[j + 1] \
             + W6 * R2_[j + 3] + W7 * R2_[j + 2] + W8 * R2_[j + 1]; \
        } \
        XF[((rr) * 18 + cidx_) * 56 + i] = (short)f2bf(v_); \
      } } }

    LOADROW(Ra, y0 - 3)   // row y-2 for rr=0
    LOADROW(Rb, y0 - 2)   // row y-1 for rr=0
#pragma unroll
    for (int rr = 0; rr < 18; rr += 3) {
      LOADROW(Rc, y0 - 1 + rr)  EMIT(rr,     Ra, Rb, Rc)
      LOADROW(Ra, y0 + rr)      EMIT(rr + 1, Rb, Rc, Ra)
      LOADROW(Rb, y0 + 1 + rr)  EMIT(rr + 2, Rc, Ra, Rb)
    }
#undef LOADROW
#undef EMIT
  }
  __syncthreads();

  // ---- phase 2: MFMA GEMM, 16x16x32_bf16 only, A-prefetch ----
  int wv = tid >> 6, lane = tid & 63;
  int tx = lane & 15, gq = lane >> 4;   // gq in 0..3
  f32x4 acc[4][3];
#pragma unroll
  for (int nn = 0; nn < 4; ++nn)
#pragma unroll
    for (int m = 0; m < 3; ++m) acc[nn][m] = (f32x4){0.f, 0.f, 0.f, 0.f};

  const unsigned short* abase = wbf64 + (tx)*64;   // + (k*48+m*16)*64
  bf16x8 Ac0[3], Ac1[3], An0[3], An1[3];
#pragma unroll
  for (int m = 0; m < 3; ++m) {
    const unsigned short* ap = abase + (0 * 48 + m * 16) * 64;
    Ac0[m] = *(const bf16x8*)(ap + gq * 8);
    Ac1[m] = *(const bf16x8*)(ap + 32 + gq * 8);
  }

  for (int k = 0; k < 9; ++k) {
    if (k < 8) {
#pragma unroll
      for (int m = 0; m < 3; ++m) {
        const unsigned short* ap = abase + ((k + 1) * 48 + m * 16) * 64;
        An0[m] = *(const bf16x8*)(ap + gq * 8);
        An1[m] = *(const bf16x8*)(ap + 32 + gq * 8);
      }
    }
    int dy = k / 3, dx = k - dy * 3;
#pragma unroll
    for (int nn = 0; nn < 4; ++nn) {
      int n = wv * 4 + nn;   // output y-row within 16x16 tile
      const short* bp = XF + ((n + dy) * 18 + tx + dx) * 56;
      bf16x8 B0 = *(const bf16x8*)(bp + gq * 8);
      bf16x8 B1 = *(const bf16x8*)(bp + 32 + gq * 8);  // i>=48: zeroed pad / next-row data, A=0
#pragma unroll
      for (int m = 0; m < 3; ++m) {
        acc[nn][m] = __builtin_amdgcn_mfma_f32_16x16x32_bf16(Ac0[m], B0, acc[nn][m], 0, 0, 0);
        acc[nn][m] = __builtin_amdgcn_mfma_f32_16x16x32_bf16(Ac1[m], B1, acc[nn][m], 0, 0, 0);
      }
    }
#pragma unroll
    for (int m = 0; m < 3; ++m) { Ac0[m] = An0[m]; Ac1[m] = An1[m]; }
  }

  // ---- epilogue: C frag layout col=lane&15 (pixel x), row=gq*4+r (oc) ----
#pragma unroll
  for (int nn = 0; nn < 4; ++nn) {
    int y = y0 + wv * 4 + nn;
#pragma unroll
    for (int m = 0; m < 3; ++m) {
#pragma unroll
      for (int r = 0; r < 4; ++r) {
        int oc = m * 16 + gq * 4 + r;
        out[((size_t)(o * COUT + oc) << 14) + (y << 7) + x0 + tx] = acc[nn][m][r];
      }
    }
  }
}

// ---------------------------------------------------------------------------
extern "C" void kernel_launch(void* const* d_in, const int* in_sizes, int n_in,
                              void* d_out, int out_size, void* d_ws, size_t ws_size,
                              hipStream_t stream)
{
  const float* x      = (const float*)d_in[0];
  const float* freq   = (const float*)d_in[1];
  const float* theta  = (const float*)d_in[2];
  const float* sigma  = (const float*)d_in[3];
  const float* psi    = (const float*)d_in[4];
  const float* f0     = (const float*)d_in[5];
  const float* theta0 = (const float*)d_in[6];
  float* out = (float*)d_out;
  float* ws  = (float*)d_ws;

  // ws layout (floats):
  // w[20736] | ar[128] | ai[128] | pad | Up[48*16384*2] | yf[48*16384] | wbf64
  float*  w   = ws;
  float*  ar  = ws + 20736;
  float*  ai  = ws + 20864;
  float2* Up  = (float2*)(ws + 21248);
  float*  yf  = ws + 21248 + CIN * NPIX * 2;
  unsigned short* wbf64 = (unsigned short*)(ws + 21248 + CIN * NPIX * 3);

  gabor_k<<<dim3(81), dim3(256), 0, stream>>>(freq, theta, sigma, psi, f0, theta0, w, wbf64);
  circ_k<<<dim3(1), dim3(128), 0, stream>>>(ar, ai);
  stage1_k<<<dim3(8, 48), dim3(256), 0, stream>>>(x, ar, ai, Up);
  stage2_k<<<dim3(8, 48), dim3(256), 0, stream>>>(Up, ar, ai, yf);
  conv2_k<<<dim3(8, 8, 48), dim3(256), 0, stream>>>(yf, w, wbf64, out);
}